// Round 12
// baseline (297.608 us; speedup 1.0000x reference)
//
#include <hip/hip_runtime.h>

// ---------------------------------------------------------------------------
// Res_NL pansharpening network, B=1, H=W=128, f32 in/out. 6 dispatches:
//   prep_k     : features + weight slabs + 3 B-offset tables + border zeroing
//   headsasm_k : all 3 attention heads per 8x8 tile + mlp + resu/respan -> x
//   rbfused_k  : one res block (conv1+conv2) per dispatch, halo recompute,
//                f in LDS, MFMA implicit GEMM, ping-pong padded bf16 buffers
//   convr_k    : recon conv 42->8
// Activations padded [42][132][144] u16 (2-halo, 16B-aligned rows).
// ---------------------------------------------------------------------------

#define DEV __device__ __forceinline__
typedef float f32x4 __attribute__((ext_vector_type(4)));
typedef __bf16 bf16x8 __attribute__((ext_vector_type(8)));
typedef unsigned short u16;
typedef unsigned int u32;

constexpr int N = 128 * 128;

// ---- workspace layout (float offsets) -------------------------------------
constexpr int OFF_PHI1 =   0 * N;   // 3 ch
constexpr int OFF_TH1  =   3 * N;   // 3 ch
constexpr int OFF_PHI2 =   6 * N;   // 5 ch
constexpr int OFF_TH2  =  11 * N;   // 5 ch
constexpr int OFF_PHI3 =  16 * N;   // 8 ch
constexpr int OFF_TH3  =  24 * N;   // 8 ch
constexpr int OFF_G1   =  32 * N;   // 5 ch
constexpr int OFF_G2   =  37 * N;   // 5 ch
constexpr int OFF_G3   =  42 * N;   // 5 ch
constexpr int OFF_X    =  47 * N;   // 42 ch f32 (skip path)
constexpr int XPLANE   = 132 * 144;           // 19008 u16 per channel
constexpr int OFF_XPA  = 110 * N;             // padded bf16 buffer A
constexpr int OFF_XPB  = 135 * N;             // padded bf16 buffer B
constexpr int OFF_SLAB = 160 * N;             // u16[116736]
constexpr int OFF_BTAB = 164 * N;             // u16[1152]: A(0) B(384) C(768)
constexpr int SLAB_RB  = 18432;
constexpr int SLAB_RC  = 110592;
constexpr int SLAB_TOT = 116736;
constexpr int ZPB      = 2624;                // border u16 per plane
constexpr int ZTOT     = 2 * 42 * ZPB;        // both buffers
constexpr int WPREP_TOT = 1152 + SLAB_TOT + ZTOT;   // 337,344... computed below
constexpr int WPREP_BLK = (WPREP_TOT + 255) / 256;

DEV bool inb(int y, int x) { return (unsigned)y < 128u && (unsigned)x < 128u; }
DEV u16 f2bf(float f) {
    unsigned u = __float_as_uint(f);
    return (u16)((u + 0x7fffu + ((u >> 16) & 1u)) >> 16);
}

struct PrepArgs {
    const float* u;    const float* pan;  const float* wnlu; const float* wnlpan;
    const float* gphi; const float* gth;  const float* gg;   const float* sphi;
    const float* sth;  const float* sg;   const float* mphi; const float* mth;
    const float* mg;
    const float* w[7];     // rb0w1,rb0w2,rb1w1,rb1w2,rb2w1,rb2w2,recon
};

// ---------------------------------------------------------------------------
// K1: prep. blocks 0..127: features. rest: slabs + 3 btabs + border zeroing.
// A-layout per lane: A[m=lane&15][k=(lane>>4)*8+j], k = ic*9+tau.
// btabA (stage1, x tile 5x72):  ic*360 + (tau/3)*72 + tau%3
// btabB (stage2, f tile 3x72):  ic*216 + (tau/3)*72 + tau%3
// btabC (recon,  x tile 3x40):  ic*120 + (tau/3)*40 + tau%3 + 1
// ---------------------------------------------------------------------------
__global__ __launch_bounds__(256) void prep_k(PrepArgs pa, float* __restrict__ ws,
                                              u16* __restrict__ slab,
                                              u16* __restrict__ btab,
                                              u16* __restrict__ xpa,
                                              u16* __restrict__ xpb) {
    const int bid = blockIdx.x, t = threadIdx.x;
    if (bid < 128) {
        const int p = (bid & 63) * 256 + t;
        const int y = p >> 7, x = p & 127;

        float uv[8][9];
#pragma unroll
        for (int ic = 0; ic < 8; ++ic)
#pragma unroll
            for (int i = 0; i < 3; ++i)
#pragma unroll
                for (int j = 0; j < 3; ++j) {
                    int yy = y + i - 1, xx = x + j - 1;
                    uv[ic][i * 3 + j] =
                        inb(yy, xx) ? pa.u[ic * N + yy * 128 + xx] : 0.f;
                }
        float uf[5] = {0, 0, 0, 0, 0};
#pragma unroll
        for (int ic = 0; ic < 8; ++ic)
#pragma unroll
            for (int k = 0; k < 9; ++k)
#pragma unroll
                for (int o = 0; o < 5; ++o)
                    uf[o] = fmaf(uv[ic][k], pa.wnlu[(o * 8 + ic) * 9 + k], uf[o]);

        if (bid < 64) {
#pragma unroll
            for (int o = 0; o < 5; ++o) {
                float a = 0, b = 0, c1 = 0, c2 = 0, c3 = 0;
#pragma unroll
                for (int i = 0; i < 5; ++i) {
                    a  = fmaf(pa.sphi[o * 5 + i], uf[i], a);
                    b  = fmaf(pa.sth [o * 5 + i], uf[i], b);
                    c1 = fmaf(pa.gg  [o * 5 + i], uf[i], c1);
                    c2 = fmaf(pa.sg  [o * 5 + i], uf[i], c2);
                    c3 = fmaf(pa.mg  [o * 5 + i], uf[i], c3);
                }
                ws[OFF_PHI2 + o * N + p] = a;
                ws[OFF_TH2  + o * N + p] = b;
                ws[OFF_G1   + o * N + p] = c1;
                ws[OFF_G2   + o * N + p] = c2;
                ws[OFF_G3   + o * N + p] = c3;
            }
        } else {
            float pv[9];
#pragma unroll
            for (int i = 0; i < 3; ++i)
#pragma unroll
                for (int j = 0; j < 3; ++j) {
                    int yy = y + i - 1, xx = x + j - 1;
                    pv[i * 3 + j] = inb(yy, xx) ? pa.pan[yy * 128 + xx] : 0.f;
                }
            float pf[3] = {0, 0, 0};
#pragma unroll
            for (int k = 0; k < 9; ++k)
#pragma unroll
                for (int o = 0; o < 3; ++o)
                    pf[o] = fmaf(pv[k], pa.wnlpan[o * 9 + k], pf[o]);
            float cat[8] = {uf[0], uf[1], uf[2], uf[3], uf[4],
                            pf[0], pf[1], pf[2]};
#pragma unroll
            for (int o = 0; o < 3; ++o) {
                float a = 0, b = 0;
#pragma unroll
                for (int i = 0; i < 3; ++i) {
                    a = fmaf(pa.gphi[o * 3 + i], pf[i], a);
                    b = fmaf(pa.gth [o * 3 + i], pf[i], b);
                }
                ws[OFF_PHI1 + o * N + p] = a;
                ws[OFF_TH1  + o * N + p] = b;
            }
#pragma unroll
            for (int o = 0; o < 8; ++o) {
                float a = 0, b = 0;
#pragma unroll
                for (int i = 0; i < 8; ++i) {
                    a = fmaf(pa.mphi[o * 8 + i], cat[i], a);
                    b = fmaf(pa.mth [o * 8 + i], cat[i], b);
                }
                ws[OFF_PHI3 + o * N + p] = a;
                ws[OFF_TH3  + o * N + p] = b;
            }
        }
        return;
    }

    int idx = (bid - 128) * 256 + t;
    if (idx >= WPREP_TOT) return;
    if (idx < 1152) {
        int which = idx / 384, k = idx - which * 384;
        u16 v = 0;
        if (k < 378) {
            int ic = k / 9, tau = k - ic * 9, i = tau / 3, j = tau - i * 3;
            if (which == 0)      v = (u16)(ic * 360 + i * 72 + j);
            else if (which == 1) v = (u16)(ic * 216 + i * 72 + j);
            else                 v = (u16)(ic * 120 + i * 40 + j + 1);
        }
        btab[idx] = v;
        return;
    }
    idx -= 1152;
    if (idx < SLAB_TOT) {
        const float* W;
        int mt, ks, lane, j, ocv;
        if (idx < SLAB_RC) {
            int cv = idx / SLAB_RB, r = idx - cv * SLAB_RB;
            mt = r / 6144; r -= mt * 6144;
            ks = r / 512;  r -= ks * 512;
            lane = r / 8;  j = r - lane * 8;
            W = pa.w[cv]; ocv = 42;
        } else {
            int r = idx - SLAB_RC;
            mt = 0;
            ks = r / 512;  r -= ks * 512;
            lane = r / 8;  j = r - lane * 8;
            W = pa.w[6]; ocv = 8;
        }
        int k  = ks * 32 + (lane >> 4) * 8 + j;
        int oc = mt * 16 + (lane & 15);
        u16 v = 0;
        if (k < 378 && oc < ocv) {
            int ic = k / 9, tau = k - ic * 9;
            v = f2bf(W[(oc * 42 + ic) * 9 + tau]);
        }
        slab[idx] = v;
        return;
    }
    idx -= SLAB_TOT;
    u16* buf = (idx < 42 * ZPB) ? xpa : xpb;
    int e = (idx < 42 * ZPB) ? idx : idx - 42 * ZPB;
    int plane = e / ZPB, rem = e - plane * ZPB;
    int row, col;
    if (rem < 576) {
        int rr = rem / 144;
        row = (rr < 2) ? rr : rr + 128;        // rows 0,1,130,131
        col = rem - rr * 144;
    } else {
        int r2 = rem - 576;
        row = 2 + r2 / 16;
        int ci = r2 & 15;
        col = (ci < 2) ? ci : 128 + ci;        // cols 0,1,130..143
    }
    buf[plane * XPLANE + row * 144 + col] = 0;
}

// ---------------------------------------------------------------------------
// K2: heads+assemble. Block = 8x8 tile, 128 threads (2/pixel). Runs all 3
// heads sequentially (LDS reused), results in registers; then mlp combine +
// resu/respan; writes x f32 + padded bf16.
// ---------------------------------------------------------------------------
template <int C, int P>
DEV void head_tile(const float* __restrict__ phi, const float* __restrict__ theta,
                   const float* __restrict__ g, float* __restrict__ smem,
                   int ty0, int tx0, int t, float ohv[5]) {
    constexpr int PR  = P / 2;
    constexpr int H3  = 3 + PR;
    constexpr int W   = 6 + P;
    constexpr int TTH = 8 + 2 * PR, TTW = 8 + 2 * PR;
    constexpr int PTH = 8 + 2 * H3, PTW = 8 + 2 * H3;
    constexpr int GTH = 14, GTW = 14;

    float* sT = smem;
    float* sP = sT + C * TTH * TTW;
    float* sG = sP + C * PTH * PTW;

    __syncthreads();   // previous head's reads done before restaging
#pragma unroll
    for (int c = 0; c < C; ++c)
#pragma unroll
        for (int base = 0; base < TTH * TTW; base += 128) {
            int i = base + t;
            if (i < TTH * TTW) {
                int r = i / TTW, cc = i - r * TTW;
                int gy = ty0 - PR + r, gx = tx0 - PR + cc;
                sT[c * TTH * TTW + i] =
                    inb(gy, gx) ? theta[c * N + gy * 128 + gx] : 0.f;
            }
        }
#pragma unroll
    for (int c = 0; c < C; ++c)
#pragma unroll
        for (int base = 0; base < PTH * PTW; base += 128) {
            int i = base + t;
            if (i < PTH * PTW) {
                int r = i / PTW, cc = i - r * PTW;
                int gy = ty0 - H3 + r, gx = tx0 - H3 + cc;
                sP[c * PTH * PTW + i] =
                    inb(gy, gx) ? phi[c * N + gy * 128 + gx] : 0.f;
            }
        }
#pragma unroll
    for (int c = 0; c < 5; ++c)
#pragma unroll
        for (int base = 0; base < GTH * GTW; base += 128) {
            int i = base + t;
            if (i < GTH * GTW) {
                int r = i / GTW, cc = i - r * GTW;
                int gy = ty0 - 3 + r, gx = tx0 - 3 + cc;
                sG[c * GTH * GTW + i] =
                    inb(gy, gx) ? g[c * N + gy * 128 + gx] : 0.f;
            }
        }
    __syncthreads();

    const int wave = t >> 6, lane = t & 63, m = lane >> 5;
    const int pidx = (lane & 31) | (wave << 5);     // 0..63
    const int py = pidx >> 3, px = pidx & 7;
    const int gy = ty0 + py, gx = tx0 + px;
    const int dbase = m * 3;

    float s[28];
#pragma unroll
    for (int k = 0; k < 28; ++k) s[k] = 0.f;

    for (int c = 0; c < C; ++c) {
        const float* tc = sT + c * TTH * TTW;
        const float* pc = sP + c * PTH * PTW;
        float T[P][P];
#pragma unroll
        for (int i = 0; i < P; ++i)
#pragma unroll
            for (int j = 0; j < P; ++j)
                T[i][j] = tc[(py + i) * TTW + px + j];
        float R[P][W];
#pragma unroll
        for (int r = 0; r < P; ++r)
#pragma unroll
            for (int w = 0; w < W; ++w)
                R[r][w] = pc[(py + dbase + r) * PTW + px + w];
#pragma unroll
        for (int dd = 0; dd < 4; ++dd) {
#pragma unroll
            for (int dx = 0; dx < 7; ++dx) {
                float a = 0.f;
#pragma unroll
                for (int i = 0; i < P; ++i)
#pragma unroll
                    for (int j = 0; j < P; ++j)
                        a = fmaf(T[i][j], R[i][dx + j], a);
                s[dd * 7 + dx] += a;
            }
            if (dd < 3) {
#pragma unroll
                for (int r = 0; r < P - 1; ++r)
#pragma unroll
                    for (int w = 0; w < W; ++w) R[r][w] = R[r + 1][w];
                int row = py + dbase + dd + P;
#pragma unroll
                for (int w = 0; w < W; ++w)
                    R[P - 1][w] = pc[row * PTW + px + w];
            }
        }
    }
#pragma unroll
    for (int k = 0; k < 28; ++k) {
        int d = dbase + k / 7, dx = k % 7;
        if (!inb(gy + d - 3, gx + dx - 3)) s[k] = 0.f;
    }
    const bool half0 = (m == 0);
    float mx = -3.0e38f;
#pragma unroll
    for (int k = 0; k < 28; ++k) {
        bool own = half0 || (k >= 7);
        mx = own ? fmaxf(mx, s[k]) : mx;
    }
    mx = fmaxf(mx, __shfl_xor(mx, 32));
    float sum = 0.f;
#pragma unroll
    for (int k = 0; k < 28; ++k) {
        bool own = half0 || (k >= 7);
        float e = own ? __expf(s[k] - mx) : 0.f;
        s[k] = e;
        sum += e;
    }
    sum += __shfl_xor(sum, 32);

    float o[5] = {0, 0, 0, 0, 0};
#pragma unroll
    for (int k = 0; k < 28; ++k) {
        int d = dbase + k / 7, dx = k % 7;
        int gr = (py + d) * GTW + px + dx;
#pragma unroll
        for (int c5 = 0; c5 < 5; ++c5)
            o[c5] = fmaf(s[k], sG[c5 * GTH * GTW + gr], o[c5]);
    }
#pragma unroll
    for (int c5 = 0; c5 < 5; ++c5) o[c5] += __shfl_xor(o[c5], 32);

    float inv = 1.f / sum;
#pragma unroll
    for (int c5 = 0; c5 < 5; ++c5) ohv[c5] = o[c5] * inv;
}

__global__ __launch_bounds__(128) void headsasm_k(
    const float* __restrict__ u, const float* __restrict__ pan,
    const float* __restrict__ wres, const float* __restrict__ wrp,
    const float* __restrict__ mlpw, const float* __restrict__ mlpb,
    float* __restrict__ ws, u16* __restrict__ xpad) {
    __shared__ float smem[3828];
    const int t = threadIdx.x;
    const int ty0 = (blockIdx.x >> 4) * 8, tx0 = (blockIdx.x & 15) * 8;

    float h1[5], h2[5], h3[5];
    head_tile<3, 3>(ws + OFF_PHI1, ws + OFF_TH1, ws + OFF_G1, smem, ty0, tx0,
                    t, h1);
    head_tile<5, 1>(ws + OFF_PHI2, ws + OFF_TH2, ws + OFF_G2, smem, ty0, tx0,
                    t, h2);
    head_tile<8, 3>(ws + OFF_PHI3, ws + OFF_TH3, ws + OFF_G3, smem, ty0, tx0,
                    t, h3);

    const int wave = t >> 6, lane = t & 63, m = lane >> 5;
    const int pidx = (lane & 31) | (wave << 5);
    const int py = pidx >> 3, px8 = pidx & 7;
    const int gy = ty0 + py, gx = tx0 + px8;
    const int p = gy * 128 + gx;
    const int padp = (gy + 2) * 144 + (gx + 2);
    float* xb = ws + OFF_X;

    if (m == 0) {
        const float w0 = mlpw[0], w1 = mlpw[1], w2 = mlpw[2];
        const float bb = mlpb[0];
#pragma unroll
        for (int c = 0; c < 5; ++c) {
            float a = h1[c] * w0 + h2[c] * w1 + h3[c] * w2 + bb;
            xb[c * N + p] = a;
            xpad[c * XPLANE + padp] = f2bf(a);
        }
    }
    // resu: m=0 -> oc 0..15, m=1 -> oc 16..31 (+respan)
    float uv[8][9];
#pragma unroll
    for (int ic = 0; ic < 8; ++ic)
#pragma unroll
        for (int i = 0; i < 3; ++i)
#pragma unroll
            for (int j = 0; j < 3; ++j) {
                int yy = gy + i - 1, xx = gx + j - 1;
                uv[ic][i * 3 + j] = inb(yy, xx) ? u[ic * N + yy * 128 + xx] : 0.f;
            }
    const int ob = m * 16;
    float acc[16];
#pragma unroll
    for (int o = 0; o < 16; ++o) acc[o] = 0.f;
#pragma unroll
    for (int ic = 0; ic < 8; ++ic)
#pragma unroll
        for (int k = 0; k < 9; ++k)
#pragma unroll
            for (int o = 0; o < 16; ++o)
                acc[o] = fmaf(uv[ic][k], wres[((ob + o) * 8 + ic) * 9 + k],
                              acc[o]);
#pragma unroll
    for (int o = 0; o < 16; ++o) {
        int ch = 5 + ob + o;
        xb[ch * N + p] = acc[o];
        xpad[ch * XPLANE + padp] = f2bf(acc[o]);
    }
    if (m == 1) {
        float pv[9];
#pragma unroll
        for (int i = 0; i < 3; ++i)
#pragma unroll
            for (int j = 0; j < 3; ++j) {
                int yy = gy + i - 1, xx = gx + j - 1;
                pv[i * 3 + j] = inb(yy, xx) ? pan[yy * 128 + xx] : 0.f;
            }
        float a5[5] = {0, 0, 0, 0, 0};
#pragma unroll
        for (int k = 0; k < 9; ++k)
#pragma unroll
            for (int o = 0; o < 5; ++o)
                a5[o] = fmaf(pv[k], wrp[o * 9 + k], a5[o]);
#pragma unroll
        for (int o = 0; o < 5; ++o) {
            int ch = 37 + o;
            xb[ch * N + p] = a5[o];
            xpad[ch * XPLANE + padp] = f2bf(a5[o]);
        }
    }
}

// ---------------------------------------------------------------------------
// K3: fused res block. Block = 64x1 output strip (grid 256, 128 thr).
// Stage x (42x5x72 padded tile) -> stage1 MFMA computes f on 3x66 halo strip
// (bias+relu, zeroed outside image) into LDS -> stage2 MFMA + bias + skip +
// relu -> writes x f32 + padded bf16 (ping-pong buffer).
// ---------------------------------------------------------------------------
__global__ __launch_bounds__(128, 1) void rbfused_k(
    const u16* __restrict__ xin, u16* __restrict__ xout,
    const u16* __restrict__ slab1, const u16* __restrict__ slab2,
    const u16* __restrict__ btab, const float* __restrict__ b1,
    const float* __restrict__ b2, float* __restrict__ xskip) {
    __shared__ __align__(16) u16 xT[15120];   // 42*5*72
    __shared__ __align__(16) u16 fT[9072];    // 42*3*72
    __shared__ __align__(16) u16 sBtA[384], sBtB[384];
    __shared__ float sB1[42], sB2[42];
    const int t = threadIdx.x;
    const int y = blockIdx.x >> 1, x0 = (blockIdx.x & 1) << 6;

    // stage x: padded rows y..y+4 (global y-2..y+2), padded cols x0..x0+71
#pragma unroll
    for (int it = 0; it < 15; ++it) {
        int c = it * 128 + t;
        if (c < 1890) {                        // 210 rows * 9 slots
            int row = c / 9, slot = c - row * 9;
            int ic = row / 5, r5 = row - ic * 5;
            uint4 v = *((const uint4*)(xin + ic * XPLANE + (y + r5) * 144 + x0)
                        + slot);
            *(uint4*)(xT + ic * 360 + r5 * 72 + slot * 8) = v;
        }
    }
#pragma unroll
    for (int it = 0; it < 3; ++it) sBtA[it * 128 + t] = btab[it * 128 + t];
#pragma unroll
    for (int it = 0; it < 3; ++it) sBtB[it * 128 + t] = btab[384 + it * 128 + t];
    if (t < 42) { sB1[t] = b1[t]; sB2[t] = b2[t]; }
    __syncthreads();

    const int lane = t & 63, wave = t >> 6;
    const int quad = lane >> 4, col = lane & 15;

    union AB { uint4 u; bf16x8 b; };
    AB a[3][12];
#pragma unroll
    for (int mt = 0; mt < 3; ++mt)
#pragma unroll
        for (int ks = 0; ks < 12; ++ks)
            a[mt][ks].u = ((const uint4*)slab1)[(mt * 12 + ks) * 64 + lane];

    // ---- stage 1: f(r=0..2, c=0..65), n = r*66+c, 13 n-tiles ----
    for (int tl = wave; tl < 13; tl += 2) {
        int n = tl * 16 + col;
        bool valid = n < 198;
        int r = n / 66, cc = n - r * 66;
        int base = valid ? r * 72 + cc : 0;
        f32x4 acc[3];
#pragma unroll
        for (int mt = 0; mt < 3; ++mt) acc[mt] = {0.f, 0.f, 0.f, 0.f};
#pragma unroll
        for (int ks = 0; ks < 12; ++ks) {
            union { uint4 u; u16 s[8]; } off;
            off.u = *(const uint4*)(sBtA + ks * 32 + quad * 8);
            union { u16 s[8]; bf16x8 b; } bv;
#pragma unroll
            for (int j = 0; j < 8; ++j) bv.s[j] = xT[off.s[j] + base];
#pragma unroll
            for (int mt = 0; mt < 3; ++mt)
                acc[mt] = __builtin_amdgcn_mfma_f32_16x16x32_bf16(
                    a[mt][ks].b, bv.b, acc[mt], 0, 0, 0);
        }
        int gy = y - 1 + r, gx = x0 - 1 + cc;
        bool img = inb(gy, gx);
#pragma unroll
        for (int mt = 0; mt < 3; ++mt)
#pragma unroll
            for (int reg = 0; reg < 4; ++reg) {
                int oc = mt * 16 + quad * 4 + reg;
                if (oc < 42 && valid) {
                    float v = fmaxf(acc[mt][reg] + sB1[oc], 0.f);
                    fT[oc * 216 + r * 72 + cc] = img ? f2bf(v) : (u16)0;
                }
            }
    }
    __syncthreads();

    // ---- stage 2: x_out over 64 cols ----
#pragma unroll
    for (int mt = 0; mt < 3; ++mt)
#pragma unroll
        for (int ks = 0; ks < 12; ++ks)
            a[mt][ks].u = ((const uint4*)slab2)[(mt * 12 + ks) * 64 + lane];

#pragma unroll
    for (int ti = 0; ti < 2; ++ti) {
        int ncol2 = (wave + 2 * ti) * 16 + col;    // 0..63
        f32x4 acc[3];
#pragma unroll
        for (int mt = 0; mt < 3; ++mt) acc[mt] = {0.f, 0.f, 0.f, 0.f};
#pragma unroll
        for (int ks = 0; ks < 12; ++ks) {
            union { uint4 u; u16 s[8]; } off;
            off.u = *(const uint4*)(sBtB + ks * 32 + quad * 8);
            union { u16 s[8]; bf16x8 b; } bv;
#pragma unroll
            for (int j = 0; j < 8; ++j) bv.s[j] = fT[off.s[j] + ncol2];
#pragma unroll
            for (int mt = 0; mt < 3; ++mt)
                acc[mt] = __builtin_amdgcn_mfma_f32_16x16x32_bf16(
                    a[mt][ks].b, bv.b, acc[mt], 0, 0, 0);
        }
        int xg = x0 + ncol2;
        int px = y * 128 + xg;
        int padp = (y + 2) * 144 + (xg + 2);
#pragma unroll
        for (int mt = 0; mt < 3; ++mt)
#pragma unroll
            for (int reg = 0; reg < 4; ++reg) {
                int oc = mt * 16 + quad * 4 + reg;
                if (oc < 42) {
                    float v = acc[mt][reg] + sB2[oc] + xskip[oc * N + px];
                    v = fmaxf(v, 0.f);
                    xskip[oc * N + px] = v;
                    xout[oc * XPLANE + padp] = f2bf(v);
                }
            }
    }
}

// ---------------------------------------------------------------------------
// K4: recon conv 42->8, padded bf16 input, 32-px strips (grid 512, 128 thr).
// ---------------------------------------------------------------------------
__global__ __launch_bounds__(128, 1) void convr_k(
    const u16* __restrict__ xin, const u16* __restrict__ slab,
    const u16* __restrict__ btab, float* __restrict__ out) {
    __shared__ __align__(16) u16 sX[5040];    // 42*3*40
    __shared__ __align__(16) u16 sBt[384];
    const int t = threadIdx.x;
    const int y = blockIdx.x >> 2, x0 = (blockIdx.x & 3) << 5;

#pragma unroll
    for (int it = 0; it < 5; ++it) {
        int c = it * 128 + t;
        if (c < 630) {                         // 126 rows * 5 slots
            int row = c / 5, slot = c - row * 5;
            int ic = row / 3, r3 = row - ic * 3;
            uint4 v = *((const uint4*)(xin + ic * XPLANE + (y + 1 + r3) * 144
                                       + x0) + slot);
            *(uint4*)(sX + row * 40 + slot * 8) = v;
        }
    }
#pragma unroll
    for (int it = 0; it < 3; ++it) sBt[it * 128 + t] = btab[768 + it * 128 + t];
    __syncthreads();

    const int lane = t & 63, wave = t >> 6;
    const int quad = lane >> 4, col = lane & 15;
    const int ncol = wave * 16 + col;          // 0..31

    union AB { uint4 u; bf16x8 b; };
    AB a[12];
#pragma unroll
    for (int ks = 0; ks < 12; ++ks)
        a[ks].u = ((const uint4*)slab)[ks * 64 + lane];

    f32x4 acc = {0.f, 0.f, 0.f, 0.f};
#pragma unroll
    for (int ks = 0; ks < 12; ++ks) {
        union { uint4 u; u16 s[8]; } off;
        off.u = *(const uint4*)(sBt + ks * 32 + quad * 8);
        union { u16 s[8]; bf16x8 b; } bv;
#pragma unroll
        for (int j = 0; j < 8; ++j) bv.s[j] = sX[off.s[j] + ncol];
        acc = __builtin_amdgcn_mfma_f32_16x16x32_bf16(a[ks].b, bv.b, acc,
                                                      0, 0, 0);
    }
    const int px = y * 128 + x0 + ncol;
#pragma unroll
    for (int reg = 0; reg < 4; ++reg) {
        int oc = quad * 4 + reg;
        if (oc < 8) out[oc * N + px] = acc[reg];
    }
}

// ---------------------------------------------------------------------------
extern "C" void kernel_launch(void* const* d_in, const int* in_sizes, int n_in,
                              void* d_out, int out_size, void* d_ws, size_t ws_size,
                              hipStream_t stream) {
    (void)in_sizes; (void)n_in; (void)out_size; (void)ws_size;
    float* ws = (float*)d_ws;
    float* out = (float*)d_out;

    PrepArgs pa;
    pa.u      = (const float*)d_in[0];
    pa.pan    = (const float*)d_in[1];
    pa.wnlu   = (const float*)d_in[2];
    pa.wnlpan = (const float*)d_in[3];
    pa.gphi   = (const float*)d_in[4];
    pa.gth    = (const float*)d_in[5];
    pa.gg     = (const float*)d_in[6];
    pa.sphi   = (const float*)d_in[7];
    pa.sth    = (const float*)d_in[8];
    pa.sg     = (const float*)d_in[9];
    pa.mphi   = (const float*)d_in[10];
    pa.mth    = (const float*)d_in[11];
    pa.mg     = (const float*)d_in[12];
    pa.w[0]   = (const float*)d_in[18];
    pa.w[1]   = (const float*)d_in[20];
    pa.w[2]   = (const float*)d_in[22];
    pa.w[3]   = (const float*)d_in[24];
    pa.w[4]   = (const float*)d_in[26];
    pa.w[5]   = (const float*)d_in[28];
    pa.w[6]   = (const float*)d_in[17];   // recon

    const float* mlpw = (const float*)d_in[13];
    const float* mlpb = (const float*)d_in[14];
    const float* wres = (const float*)d_in[15];
    const float* wrp  = (const float*)d_in[16];

    u16* xpa  = (u16*)(ws + OFF_XPA);
    u16* xpb  = (u16*)(ws + OFF_XPB);
    u16* slab = (u16*)(ws + OFF_SLAB);
    u16* btab = (u16*)(ws + OFF_BTAB);

    prep_k<<<128 + WPREP_BLK, 256, 0, stream>>>(pa, ws, slab, btab, xpa, xpb);
    headsasm_k<<<256, 128, 0, stream>>>(pa.u, pa.pan, wres, wrp, mlpw, mlpb,
                                        ws, xpa);
    // rb0: A->B, rb1: B->A, rb2: A->B
    rbfused_k<<<256, 128, 0, stream>>>(xpa, xpb, slab + 0 * SLAB_RB,
                                       slab + 1 * SLAB_RB, btab,
                                       (const float*)d_in[19],
                                       (const float*)d_in[21], ws + OFF_X);
    rbfused_k<<<256, 128, 0, stream>>>(xpb, xpa, slab + 2 * SLAB_RB,
                                       slab + 3 * SLAB_RB, btab,
                                       (const float*)d_in[23],
                                       (const float*)d_in[25], ws + OFF_X);
    rbfused_k<<<256, 128, 0, stream>>>(xpa, xpb, slab + 4 * SLAB_RB,
                                       slab + 5 * SLAB_RB, btab,
                                       (const float*)d_in[27],
                                       (const float*)d_in[29], ws + OFF_X);
    convr_k<<<512, 128, 0, stream>>>(xpb, slab + SLAB_RC, btab, out);
}

// Round 13
// 208.852 us; speedup vs baseline: 1.4250x; 1.4250x over previous
//
#include <hip/hip_runtime.h>

// ---------------------------------------------------------------------------
// Res_NL pansharpening network, B=1, H=W=128, f32 in/out. 11 dispatches
// (R11 structure — fusion measured slower). Width over fusion:
//   prep_k     : features 4-way output-split (256 blk) + weight slabs + btab
//                + pad-border zeroing
//   heads_k    : 3 attention heads, 8x8 tiles, 4 threads/pixel
//                (d-row split x channel split, shfl-combined), grid (256,3)
//   assemble_k : mlp combine + resu/respan; writes x f32 + padded bf16
//   convm_k    : implicit-GEMM conv, m-tiles split across waves: 384-thr
//                blocks (6 waves = 2 px-halves x 3 oc-tiles), grid 512
//   convr_k    : recon conv 42->8
// Activations padded [42][130][136] u16 (1-halo, 16B-aligned rows).
// ---------------------------------------------------------------------------

#define DEV __device__ __forceinline__
typedef float f32x4 __attribute__((ext_vector_type(4)));
typedef __bf16 bf16x8 __attribute__((ext_vector_type(8)));
typedef unsigned short u16;
typedef unsigned int u32;

constexpr int N = 128 * 128;

// ---- workspace layout (float offsets) -------------------------------------
constexpr int OFF_PHI1 =   0 * N;   // 3 ch
constexpr int OFF_TH1  =   3 * N;   // 3 ch
constexpr int OFF_PHI2 =   6 * N;   // 5 ch
constexpr int OFF_TH2  =  11 * N;   // 5 ch
constexpr int OFF_PHI3 =  16 * N;   // 8 ch
constexpr int OFF_TH3  =  24 * N;   // 8 ch
constexpr int OFF_G1   =  32 * N;   // 5 ch
constexpr int OFF_G2   =  37 * N;   // 5 ch
constexpr int OFF_G3   =  42 * N;   // 5 ch
constexpr int OFF_X    =  47 * N;   // 42 ch f32 (skip path)
constexpr int OFF_OH1  =  89 * N;   // 5 ch
constexpr int OFF_OH2  =  94 * N;   // 5 ch
constexpr int OFF_OH3  =  99 * N;   // 5 ch
constexpr int XPLANE   = 130 * 136;           // 17680 u16 per channel
constexpr int OFF_XPAD = 110 * N;
constexpr int OFF_FPAD = 133 * N;
constexpr int OFF_SLAB = 156 * N;             // u16[116736]
constexpr int OFF_BTAB = 160 * N;             // u16[384]
constexpr int SLAB_RB  = 18432;
constexpr int SLAB_RC  = 110592;
constexpr int SLAB_TOT = 116736;
constexpr int ZPB      = 528;                 // border u16 per plane
constexpr int ZTOT     = 2 * 42 * ZPB;
constexpr int WPREP_TOT = 384 + SLAB_TOT + ZTOT;   // 161472
constexpr int WPREP_BLK = (WPREP_TOT + 255) / 256; // 631

DEV bool inb(int y, int x) { return (unsigned)y < 128u && (unsigned)x < 128u; }
DEV u16 f2bf(float f) {
    unsigned u = __float_as_uint(f);
    return (u16)((u + 0x7fffu + ((u >> 16) & 1u)) >> 16);
}

struct PrepArgs {
    const float* u;    const float* pan;  const float* wnlu; const float* wnlpan;
    const float* gphi; const float* gth;  const float* gg;   const float* sphi;
    const float* sth;  const float* sg;   const float* mphi; const float* mth;
    const float* mg;
    const float* w[7];     // rb0w1,rb0w2,rb1w1,rb1w2,rb2w1,rb2w2,recon
};

// ---------------------------------------------------------------------------
// K1: prep. blocks 0..255: features in 4 output groups (uf conv duplicated,
// latency-bound so duplication ~free, parallelism 2x R11):
//   g0: phi2/th2/g1   g1: g2/g3   g2: phi1/th1/phi3   g3: th3
// blocks 256..: bf16 MFMA A-slabs + btab + pad-border zeroing.
// A per lane: A[m=lane&15][k=(lane>>4)*8+j], k=ic*9+tau.
// btab[k] = ic*120 + (tau/3)*40 + tau%3 (LDS tile row stride 40 u16).
// ---------------------------------------------------------------------------
__global__ __launch_bounds__(256) void prep_k(PrepArgs pa, float* __restrict__ ws,
                                              u16* __restrict__ slab,
                                              u16* __restrict__ btab,
                                              u16* __restrict__ xpad,
                                              u16* __restrict__ fpad) {
    const int bid = blockIdx.x, t = threadIdx.x;
    if (bid < 256) {
        const int g = bid >> 6;
        const int p = (bid & 63) * 256 + t;
        const int y = p >> 7, x = p & 127;

        float uv[8][9];
#pragma unroll
        for (int ic = 0; ic < 8; ++ic)
#pragma unroll
            for (int i = 0; i < 3; ++i)
#pragma unroll
                for (int j = 0; j < 3; ++j) {
                    int yy = y + i - 1, xx = x + j - 1;
                    uv[ic][i * 3 + j] =
                        inb(yy, xx) ? pa.u[ic * N + yy * 128 + xx] : 0.f;
                }
        float uf[5] = {0, 0, 0, 0, 0};
#pragma unroll
        for (int ic = 0; ic < 8; ++ic)
#pragma unroll
            for (int k = 0; k < 9; ++k)
#pragma unroll
                for (int o = 0; o < 5; ++o)
                    uf[o] = fmaf(uv[ic][k], pa.wnlu[(o * 8 + ic) * 9 + k], uf[o]);

        if (g == 0) {
#pragma unroll
            for (int o = 0; o < 5; ++o) {
                float a = 0, b = 0, c1 = 0;
#pragma unroll
                for (int i = 0; i < 5; ++i) {
                    a  = fmaf(pa.sphi[o * 5 + i], uf[i], a);
                    b  = fmaf(pa.sth [o * 5 + i], uf[i], b);
                    c1 = fmaf(pa.gg  [o * 5 + i], uf[i], c1);
                }
                ws[OFF_PHI2 + o * N + p] = a;
                ws[OFF_TH2  + o * N + p] = b;
                ws[OFF_G1   + o * N + p] = c1;
            }
        } else if (g == 1) {
#pragma unroll
            for (int o = 0; o < 5; ++o) {
                float c2 = 0, c3 = 0;
#pragma unroll
                for (int i = 0; i < 5; ++i) {
                    c2 = fmaf(pa.sg[o * 5 + i], uf[i], c2);
                    c3 = fmaf(pa.mg[o * 5 + i], uf[i], c3);
                }
                ws[OFF_G2 + o * N + p] = c2;
                ws[OFF_G3 + o * N + p] = c3;
            }
        } else {
            float pv[9];
#pragma unroll
            for (int i = 0; i < 3; ++i)
#pragma unroll
                for (int j = 0; j < 3; ++j) {
                    int yy = y + i - 1, xx = x + j - 1;
                    pv[i * 3 + j] = inb(yy, xx) ? pa.pan[yy * 128 + xx] : 0.f;
                }
            float pf[3] = {0, 0, 0};
#pragma unroll
            for (int k = 0; k < 9; ++k)
#pragma unroll
                for (int o = 0; o < 3; ++o)
                    pf[o] = fmaf(pv[k], pa.wnlpan[o * 9 + k], pf[o]);
            float cat[8] = {uf[0], uf[1], uf[2], uf[3], uf[4],
                            pf[0], pf[1], pf[2]};
            if (g == 2) {
#pragma unroll
                for (int o = 0; o < 3; ++o) {
                    float a = 0, b = 0;
#pragma unroll
                    for (int i = 0; i < 3; ++i) {
                        a = fmaf(pa.gphi[o * 3 + i], pf[i], a);
                        b = fmaf(pa.gth [o * 3 + i], pf[i], b);
                    }
                    ws[OFF_PHI1 + o * N + p] = a;
                    ws[OFF_TH1  + o * N + p] = b;
                }
#pragma unroll
                for (int o = 0; o < 8; ++o) {
                    float a = 0;
#pragma unroll
                    for (int i = 0; i < 8; ++i)
                        a = fmaf(pa.mphi[o * 8 + i], cat[i], a);
                    ws[OFF_PHI3 + o * N + p] = a;
                }
            } else {
#pragma unroll
                for (int o = 0; o < 8; ++o) {
                    float b = 0;
#pragma unroll
                    for (int i = 0; i < 8; ++i)
                        b = fmaf(pa.mth[o * 8 + i], cat[i], b);
                    ws[OFF_TH3 + o * N + p] = b;
                }
            }
        }
        return;
    }

    int idx = (bid - 256) * 256 + t;
    if (idx >= WPREP_TOT) return;
    if (idx < 384) {
        u16 v = 0;
        if (idx < 378) {
            int ic = idx / 9, tau = idx - ic * 9;
            v = (u16)(ic * 120 + (tau / 3) * 40 + (tau % 3));
        }
        btab[idx] = v;
        return;
    }
    idx -= 384;
    if (idx < SLAB_TOT) {
        const float* W;
        int mt, ks, lane, j, ocv;
        if (idx < SLAB_RC) {
            int cv = idx / SLAB_RB, r = idx - cv * SLAB_RB;
            mt = r / 6144; r -= mt * 6144;
            ks = r / 512;  r -= ks * 512;
            lane = r / 8;  j = r - lane * 8;
            W = pa.w[cv]; ocv = 42;
        } else {
            int r = idx - SLAB_RC;
            mt = 0;
            ks = r / 512;  r -= ks * 512;
            lane = r / 8;  j = r - lane * 8;
            W = pa.w[6]; ocv = 8;
        }
        int k  = ks * 32 + (lane >> 4) * 8 + j;
        int oc = mt * 16 + (lane & 15);
        u16 v = 0;
        if (k < 378 && oc < ocv) {
            int ic = k / 9, tau = k - ic * 9;
            v = f2bf(W[(oc * 42 + ic) * 9 + tau]);
        }
        slab[idx] = v;
        return;
    }
    idx -= SLAB_TOT;
    u16* buf = (idx < 42 * ZPB) ? xpad : fpad;
    int e = (idx < 42 * ZPB) ? idx : idx - 42 * ZPB;
    int plane = e / ZPB, rem = e - plane * ZPB;
    int row, col;
    if (rem < 136)      { row = 0;             col = rem; }
    else if (rem < 272) { row = 129;           col = rem - 136; }
    else if (rem < 400) { row = 1 + rem - 272; col = 0; }
    else                { row = 1 + rem - 400; col = 129; }
    buf[plane * XPLANE + row * 136 + col] = 0;
}

// ---------------------------------------------------------------------------
// K2: attention heads, 8x8 tiles, 256 threads = 4 per pixel:
//   h = (lane>>4)&1 : channel half (score partial, combined via shfl_xor 16)
//   m = lane>>5     : neighbor-row half (softmax/PV merged via shfl_xor 32)
// PV also channel-split: h=0 -> g ch 0..2, h=1 -> ch 3..4.
// ---------------------------------------------------------------------------
template <int C, int P>
DEV void head_tile(const float* __restrict__ phi, const float* __restrict__ theta,
                   const float* __restrict__ g, float* __restrict__ oh,
                   float* __restrict__ smem, int ty0, int tx0, int t) {
    constexpr int PR  = P / 2;
    constexpr int H3  = 3 + PR;
    constexpr int W   = 6 + P;
    constexpr int TTH = 8 + 2 * PR, TTW = 8 + 2 * PR;
    constexpr int PTH = 8 + 2 * H3, PTW = 8 + 2 * H3;
    constexpr int GTH = 14, GTW = 14;
    constexpr int CH0 = (C + 1) / 2;

    float* sT = smem;
    float* sP = sT + C * TTH * TTW;
    float* sG = sP + C * PTH * PTW;

#pragma unroll
    for (int c = 0; c < C; ++c) {
        int i = t;
        if (i < TTH * TTW) {
            int r = i / TTW, cc = i - r * TTW;
            int gy = ty0 - PR + r, gx = tx0 - PR + cc;
            sT[c * TTH * TTW + i] =
                inb(gy, gx) ? theta[c * N + gy * 128 + gx] : 0.f;
        }
    }
#pragma unroll
    for (int c = 0; c < C; ++c) {
        int i = t;
        if (i < PTH * PTW) {
            int r = i / PTW, cc = i - r * PTW;
            int gy = ty0 - H3 + r, gx = tx0 - H3 + cc;
            sP[c * PTH * PTW + i] =
                inb(gy, gx) ? phi[c * N + gy * 128 + gx] : 0.f;
        }
    }
#pragma unroll
    for (int c = 0; c < 5; ++c) {
        int i = t;
        if (i < GTH * GTW) {
            int r = i / GTW, cc = i - r * GTW;
            int gy = ty0 - 3 + r, gx = tx0 - 3 + cc;
            sG[c * GTH * GTW + i] =
                inb(gy, gx) ? g[c * N + gy * 128 + gx] : 0.f;
        }
    }
    __syncthreads();

    const int lane = t & 63, wave = t >> 6;
    const int h = (lane >> 4) & 1, m = lane >> 5;
    const int pidx = wave * 16 + (lane & 15);       // 0..63
    const int py = pidx >> 3, px = pidx & 7;
    const int gy = ty0 + py, gx = tx0 + px;
    const int dbase = m * 3;
    const int cbeg = h ? CH0 : 0, cend = h ? C : CH0;

    float s[28];
#pragma unroll
    for (int k = 0; k < 28; ++k) s[k] = 0.f;

#pragma unroll
    for (int ci = 0; ci < CH0; ++ci) {
        int c = cbeg + ci;
        bool cok = c < cend;
        const float* tc = sT + (cok ? c : 0) * TTH * TTW;
        const float* pc = sP + (cok ? c : 0) * PTH * PTW;
        float T[P][P];
#pragma unroll
        for (int i = 0; i < P; ++i)
#pragma unroll
            for (int j = 0; j < P; ++j)
                T[i][j] = cok ? tc[(py + i) * TTW + px + j] : 0.f;
        float R[P][W];
#pragma unroll
        for (int r = 0; r < P; ++r)
#pragma unroll
            for (int w = 0; w < W; ++w)
                R[r][w] = pc[(py + dbase + r) * PTW + px + w];
#pragma unroll
        for (int dd = 0; dd < 4; ++dd) {
#pragma unroll
            for (int dx = 0; dx < 7; ++dx) {
                float a = 0.f;
#pragma unroll
                for (int i = 0; i < P; ++i)
#pragma unroll
                    for (int j = 0; j < P; ++j)
                        a = fmaf(T[i][j], R[i][dx + j], a);
                s[dd * 7 + dx] += a;
            }
            if (dd < 3) {
#pragma unroll
                for (int r = 0; r < P - 1; ++r)
#pragma unroll
                    for (int w = 0; w < W; ++w) R[r][w] = R[r + 1][w];
                int row = py + dbase + dd + P;
#pragma unroll
                for (int w = 0; w < W; ++w)
                    R[P - 1][w] = pc[row * PTW + px + w];
            }
        }
    }
    // combine channel halves (partner: same pixel, same m, other h)
#pragma unroll
    for (int k = 0; k < 28; ++k) s[k] += __shfl_xor(s[k], 16);

#pragma unroll
    for (int k = 0; k < 28; ++k) {
        int d = dbase + k / 7, dx = k % 7;
        if (!inb(gy + d - 3, gx + dx - 3)) s[k] = 0.f;
    }
    const bool half0 = (m == 0);
    float mx = -3.0e38f;
#pragma unroll
    for (int k = 0; k < 28; ++k) {
        bool own = half0 || (k >= 7);
        mx = own ? fmaxf(mx, s[k]) : mx;
    }
    mx = fmaxf(mx, __shfl_xor(mx, 32));
    float sum = 0.f;
#pragma unroll
    for (int k = 0; k < 28; ++k) {
        bool own = half0 || (k >= 7);
        float e = own ? __expf(s[k] - mx) : 0.f;
        s[k] = e;
        sum += e;
    }
    sum += __shfl_xor(sum, 32);

    // PV, channel-split: h=0 -> g ch 0..2, h=1 -> 3..4
    const int gb = h ? 3 : 0, gn = h ? 2 : 3;
    float o[3] = {0, 0, 0};
#pragma unroll
    for (int k = 0; k < 28; ++k) {
        int d = dbase + k / 7, dx = k % 7;
        int gr = (py + d) * GTW + px + dx;
#pragma unroll
        for (int c5 = 0; c5 < 3; ++c5)
            if (c5 < gn)
                o[c5] = fmaf(s[k], sG[(gb + c5) * GTH * GTW + gr], o[c5]);
    }
#pragma unroll
    for (int c5 = 0; c5 < 3; ++c5) o[c5] += __shfl_xor(o[c5], 32);

    if (half0) {
        float inv = 1.f / sum;
        int p = gy * 128 + gx;
#pragma unroll
        for (int c5 = 0; c5 < 3; ++c5)
            if (c5 < gn) oh[(gb + c5) * N + p] = o[c5] * inv;
    }
}

__global__ __launch_bounds__(256) void heads_k(float* __restrict__ ws) {
    __shared__ float smem[3828];   // head3: 800 + 2048 + 980
    const int t = threadIdx.x;
    const int ty0 = (blockIdx.x >> 4) * 8, tx0 = (blockIdx.x & 15) * 8;
    if (blockIdx.y == 0)
        head_tile<3, 3>(ws + OFF_PHI1, ws + OFF_TH1, ws + OFF_G1, ws + OFF_OH1,
                        smem, ty0, tx0, t);
    else if (blockIdx.y == 1)
        head_tile<5, 1>(ws + OFF_PHI2, ws + OFF_TH2, ws + OFF_G2, ws + OFF_OH2,
                        smem, ty0, tx0, t);
    else
        head_tile<8, 3>(ws + OFF_PHI3, ws + OFF_TH3, ws + OFF_G3, ws + OFF_OH3,
                        smem, ty0, tx0, t);
}

// ---------------------------------------------------------------------------
// K3: assemble, grid (64, 5). Writes x f32 (skip) + padded bf16 (MFMA input).
// ---------------------------------------------------------------------------
__global__ __launch_bounds__(256, 2) void assemble_k(
    const float* __restrict__ u, const float* __restrict__ pan,
    const float* __restrict__ wres, const float* __restrict__ wrp,
    const float* __restrict__ mlpw, const float* __restrict__ mlpb,
    float* __restrict__ ws, u16* __restrict__ xpad) {
    const int p = blockIdx.x * 256 + threadIdx.x;
    const int y = p >> 7, x = p & 127;
    const int padp = (y + 1) * 136 + (x + 1);
    float* xb = ws + OFF_X;

    if (blockIdx.y == 0) {
        const float w0 = mlpw[0], w1 = mlpw[1], w2 = mlpw[2];
        const float bb = mlpb[0];
#pragma unroll
        for (int c = 0; c < 5; ++c) {
            float a = ws[OFF_OH1 + c * N + p] * w0 +
                      ws[OFF_OH2 + c * N + p] * w1 +
                      ws[OFF_OH3 + c * N + p] * w2 + bb;
            xb[c * N + p] = a;
            xpad[c * XPLANE + padp] = f2bf(a);
        }
        float pv[9];
#pragma unroll
        for (int i = 0; i < 3; ++i)
#pragma unroll
            for (int j = 0; j < 3; ++j) {
                int yy = y + i - 1, xx = x + j - 1;
                pv[i * 3 + j] = inb(yy, xx) ? pan[yy * 128 + xx] : 0.f;
            }
        float a5[5] = {0, 0, 0, 0, 0};
#pragma unroll
        for (int k = 0; k < 9; ++k)
#pragma unroll
            for (int o = 0; o < 5; ++o)
                a5[o] = fmaf(pv[k], wrp[o * 9 + k], a5[o]);
#pragma unroll
        for (int o = 0; o < 5; ++o) {
            xb[(37 + o) * N + p] = a5[o];
            xpad[(37 + o) * XPLANE + padp] = f2bf(a5[o]);
        }
    } else {
        const int ob = (blockIdx.y - 1) * 8;
        float uv[8][9];
#pragma unroll
        for (int ic = 0; ic < 8; ++ic)
#pragma unroll
            for (int i = 0; i < 3; ++i)
#pragma unroll
                for (int j = 0; j < 3; ++j) {
                    int yy = y + i - 1, xx = x + j - 1;
                    uv[ic][i * 3 + j] =
                        inb(yy, xx) ? u[ic * N + yy * 128 + xx] : 0.f;
                }
        float acc[8] = {0, 0, 0, 0, 0, 0, 0, 0};
#pragma unroll
        for (int ic = 0; ic < 8; ++ic)
#pragma unroll
            for (int k = 0; k < 9; ++k)
#pragma unroll
                for (int o = 0; o < 8; ++o)
                    acc[o] = fmaf(uv[ic][k], wres[((ob + o) * 8 + ic) * 9 + k],
                                  acc[o]);
#pragma unroll
        for (int o = 0; o < 8; ++o) {
            xb[(5 + ob + o) * N + p] = acc[o];
            xpad[(5 + ob + o) * XPLANE + padp] = f2bf(acc[o]);
        }
    }
}

// ---------------------------------------------------------------------------
// K4: implicit-GEMM conv on MFMA, padded bf16 input. Block = 32 px of one
// row, 384 threads = 6 waves: wave w -> px-half w/3, m-tile w%3.
// 3072 waves total (3/SIMD). Staging 630 uint4, maskless. LDS stride 40 u16.
// Bias+relu always on. D: col=lane&15 (px), row=quad*4+reg (oc).
// ---------------------------------------------------------------------------
template <bool SKIP, bool WF32, bool WPAD>
__global__ __launch_bounds__(384, 3) void convm_k(
    const u16* __restrict__ xin, const u16* __restrict__ slab,
    const u16* __restrict__ btab, const float* __restrict__ bs,
    const float* __restrict__ skip, float* __restrict__ of32,
    u16* __restrict__ opad) {
    __shared__ __align__(16) u16 sX[5040];    // 42*3*40
    __shared__ __align__(16) u16 sBt[384];
    const int t = threadIdx.x;
    const int y = blockIdx.x >> 2, x0 = (blockIdx.x & 3) << 5;

    const u16* srcbase = xin + y * 136 + x0;   // pad rows y..y+2 = img y-1..y+1
#pragma unroll
    for (int it = 0; it < 2; ++it) {
        int c = it * 384 + t;
        if (c < 630) {                         // 126 rows * 5 slots
            int row = c / 5, slot = c - row * 5;
            int ic = row / 3, r = row - ic * 3;
            uint4 v = *((const uint4*)(srcbase + ic * XPLANE + r * 136) + slot);
            *(uint4*)(sX + row * 40 + slot * 8) = v;
        }
    }
    sBt[t >= 384 ? 0 : t] = btab[t >= 384 ? 0 : t];   // t < 384 always
    __syncthreads();

    const int lane = t & 63, wave = t >> 6;
    const int ph = wave / 3, mt = wave - ph * 3;
    const int quad = lane >> 4, col = lane & 15;
    const int ncol = ph * 16 + col;            // 0..31

    union AB { uint4 u; bf16x8 b; };
    AB a[12];
#pragma unroll
    for (int ks = 0; ks < 12; ++ks)
        a[ks].u = ((const uint4*)slab)[(mt * 12 + ks) * 64 + lane];

    f32x4 acc = {0.f, 0.f, 0.f, 0.f};
#pragma unroll
    for (int ks = 0; ks < 12; ++ks) {
        union { uint4 u; u16 s[8]; } off;
        off.u = *(const uint4*)(sBt + ks * 32 + quad * 8);
        union { u16 s[8]; bf16x8 b; } bv;
#pragma unroll
        for (int j = 0; j < 8; ++j) bv.s[j] = sX[off.s[j] + ncol];
        acc = __builtin_amdgcn_mfma_f32_16x16x32_bf16(a[ks].b, bv.b, acc,
                                                      0, 0, 0);
    }

    const int xg = x0 + ncol;
    const int px = y * 128 + xg;
    const int padp = (y + 1) * 136 + (xg + 1);
#pragma unroll
    for (int reg = 0; reg < 4; ++reg) {
        int oc = mt * 16 + quad * 4 + reg;
        if (oc < 42) {
            float v = acc[reg] + bs[oc];
            if (SKIP) v += skip[oc * N + px];
            v = fmaxf(v, 0.f);
            if (WF32) of32[oc * N + px] = v;
            if (WPAD) opad[oc * XPLANE + padp] = f2bf(v);
        }
    }
}

// ---------------------------------------------------------------------------
// K5: recon conv 42->8, padded bf16 input, 32-px strips (grid 512, 128 thr).
// ---------------------------------------------------------------------------
__global__ __launch_bounds__(128, 1) void convr_k(
    const u16* __restrict__ xin, const u16* __restrict__ slab,
    const u16* __restrict__ btab, float* __restrict__ out) {
    __shared__ __align__(16) u16 sX[5040];
    __shared__ __align__(16) u16 sBt[384];
    const int t = threadIdx.x;
    const int y = blockIdx.x >> 2, x0 = (blockIdx.x & 3) << 5;

    const u16* srcbase = xin + y * 136 + x0;
#pragma unroll
    for (int it = 0; it < 5; ++it) {
        int c = it * 128 + t;
        if (c < 630) {
            int row = c / 5, slot = c - row * 5;
            int ic = row / 3, r = row - ic * 3;
            uint4 v = *((const uint4*)(srcbase + ic * XPLANE + r * 136) + slot);
            *(uint4*)(sX + row * 40 + slot * 8) = v;
        }
    }
#pragma unroll
    for (int it = 0; it < 3; ++it) sBt[it * 128 + t] = btab[it * 128 + t];
    __syncthreads();

    const int lane = t & 63, wave = t >> 6;
    const int quad = lane >> 4, col = lane & 15;
    const int ncol = wave * 16 + col;

    union AB { uint4 u; bf16x8 b; };
    AB a[12];
#pragma unroll
    for (int ks = 0; ks < 12; ++ks)
        a[ks].u = ((const uint4*)slab)[ks * 64 + lane];

    f32x4 acc = {0.f, 0.f, 0.f, 0.f};
#pragma unroll
    for (int ks = 0; ks < 12; ++ks) {
        union { uint4 u; u16 s[8]; } off;
        off.u = *(const uint4*)(sBt + ks * 32 + quad * 8);
        union { u16 s[8]; bf16x8 b; } bv;
#pragma unroll
        for (int j = 0; j < 8; ++j) bv.s[j] = sX[off.s[j] + ncol];
        acc = __builtin_amdgcn_mfma_f32_16x16x32_bf16(a[ks].b, bv.b, acc,
                                                      0, 0, 0);
    }
    const int px = y * 128 + x0 + ncol;
#pragma unroll
    for (int reg = 0; reg < 4; ++reg) {
        int oc = quad * 4 + reg;
        if (oc < 8) out[oc * N + px] = acc[reg];
    }
}

// ---------------------------------------------------------------------------
extern "C" void kernel_launch(void* const* d_in, const int* in_sizes, int n_in,
                              void* d_out, int out_size, void* d_ws, size_t ws_size,
                              hipStream_t stream) {
    (void)in_sizes; (void)n_in; (void)out_size; (void)ws_size;
    float* ws = (float*)d_ws;
    float* out = (float*)d_out;

    PrepArgs pa;
    pa.u      = (const float*)d_in[0];
    pa.pan    = (const float*)d_in[1];
    pa.wnlu   = (const float*)d_in[2];
    pa.wnlpan = (const float*)d_in[3];
    pa.gphi   = (const float*)d_in[4];
    pa.gth    = (const float*)d_in[5];
    pa.gg     = (const float*)d_in[6];
    pa.sphi   = (const float*)d_in[7];
    pa.sth    = (const float*)d_in[8];
    pa.sg     = (const float*)d_in[9];
    pa.mphi   = (const float*)d_in[10];
    pa.mth    = (const float*)d_in[11];
    pa.mg     = (const float*)d_in[12];
    pa.w[0]   = (const float*)d_in[18];
    pa.w[1]   = (const float*)d_in[20];
    pa.w[2]   = (const float*)d_in[22];
    pa.w[3]   = (const float*)d_in[24];
    pa.w[4]   = (const float*)d_in[26];
    pa.w[5]   = (const float*)d_in[28];
    pa.w[6]   = (const float*)d_in[17];   // recon

    const float* mlpw = (const float*)d_in[13];
    const float* mlpb = (const float*)d_in[14];
    const float* wres = (const float*)d_in[15];
    const float* wrp  = (const float*)d_in[16];

    u16* xpad = (u16*)(ws + OFF_XPAD);
    u16* fpad = (u16*)(ws + OFF_FPAD);
    u16* slab = (u16*)(ws + OFF_SLAB);
    u16* btab = (u16*)(ws + OFF_BTAB);

    prep_k<<<256 + WPREP_BLK, 256, 0, stream>>>(pa, ws, slab, btab, xpad, fpad);
    heads_k<<<dim3(256, 3), 256, 0, stream>>>(ws);
    assemble_k<<<dim3(64, 5), 256, 0, stream>>>(pa.u, pa.pan, wres, wrp, mlpw,
                                                mlpb, ws, xpad);

    for (int r = 0; r < 3; ++r) {
        const float* b1 = (const float*)d_in[19 + 4 * r];
        const float* b2 = (const float*)d_in[21 + 4 * r];
        convm_k<false, false, true>
            <<<512, 384, 0, stream>>>(xpad, slab + (2 * r) * SLAB_RB, btab, b1,
                                      nullptr, nullptr, fpad);
        convm_k<true, true, true>
            <<<512, 384, 0, stream>>>(fpad, slab + (2 * r + 1) * SLAB_RB, btab,
                                      b2, ws + OFF_X, ws + OFF_X, xpad);
    }
    convr_k<<<512, 128, 0, stream>>>(xpad, slab + SLAB_RC, btab, out);
}